// Round 7
// baseline (2777.878 us; speedup 1.0000x reference)
//
#include <hip/hip_runtime.h>
#include <stdint.h>
#include <stddef.h>

#define B_ 128
#define T_ 256
#define I_ 256
#define H_ 1024
#define O_ 128

typedef __attribute__((ext_vector_type(8))) __bf16 bf16x8;
typedef __attribute__((ext_vector_type(4))) float f32x4;
typedef unsigned long long u64;

// Split-plane swizzled layout (per plane of K columns, 128 rows, bf16):
//   element (b,k) at bf16 index ((b>>4)*(K/8) + (k>>3))*128 + (b&15)*8 + (k&7)
// => an MFMA A-fragment (lane ln row, k = q*8..q*8+7) is 16 contiguous bytes.
//
// Round 7 sync: per-producer monotonic flags, RMW-free.
//   flagL0[bt][jt] = t+1  after L0 block (bt,jt) completed round t (stores drained)
//   flagL1[bt][jt] = r    after L1 block (bt,jt) completed round r
// Consumers spin lane-parallel on exactly the producers of their K-chunks:
//   L0 wave w>=1: flagL0[pLo..pHi] >= t      (own-state producers, 2-5 flags)
//   L0 wave 0   : none (pure-x chunks)
//   L1 wave w<4 : flagL0[w*8 .. w*8+7] >= r  (h1 producers)
//   L1 wave w>=4: flagL1[(w-4)*8 ..+7] >= r-1 (1-round slack)
// Overwrite guards (before epilogue stores, 32-flag lane-parallel spins):
//   L0 round t: flagL0[*] >= t  AND  flagL1[*] >= t-1  (h1-alias readers)
//   L1 round r: flagL1[*] >= r-1
// All spins target strictly earlier (layer,round) completions -> acyclic.

// ---------------------------------------------------------------- setup

__global__ void split_kernel(const float* __restrict__ src, __bf16* __restrict__ hi,
                             __bf16* __restrict__ lo, int n) {
    int i = blockIdx.x * blockDim.x + threadIdx.x;
    int stride = gridDim.x * blockDim.x;
    for (; i < n; i += stride) {
        float v = src[i];
        __bf16 h = (__bf16)v;
        hi[i] = h;
        lo[i] = (__bf16)(v - (float)h);
    }
}

// X (B,T,I) fp32 -> per-t split planes in fragment layout (K=256)
__global__ void pack_x(const float* __restrict__ X, __bf16* __restrict__ xh,
                       __bf16* __restrict__ xl) {
    int i = blockIdx.x * 256 + threadIdx.x;   // 0 .. 1048575
    int lnidx = i & 15;
    int kg   = (i >> 4) & 31;
    int bgrp = (i >> 9) & 7;
    int t    = i >> 12;
    int b = bgrp * 16 + lnidx;
    const float* xs = X + (long)b * T_ * I_ + (long)t * I_ + kg * 8;
    float4 f0 = *(const float4*)xs;
    float4 f1 = *(const float4*)(xs + 4);
    float f[8] = {f0.x, f0.y, f0.z, f0.w, f1.x, f1.y, f1.z, f1.w};
    bf16x8 hv, lv;
    #pragma unroll
    for (int j = 0; j < 8; ++j) {
        __bf16 h = (__bf16)f[j];
        hv[j] = h;
        lv[j] = (__bf16)(f[j] - (float)h);
    }
    long o = (long)t * 32768 + (long)(bgrp * 32 + kg) * 128 + lnidx * 8;
    *(bf16x8*)(xh + o) = hv;
    *(bf16x8*)(xl + o) = lv;
}

__global__ void bias_sum_kernel(const float* __restrict__ a, const float* __restrict__ b,
                                float* __restrict__ o, int n) {
    int i = blockIdx.x * blockDim.x + threadIdx.x;
    if (i < n) o[i] = a[i] + b[i];
}

__global__ void transpose_fc(const float* __restrict__ w, float* __restrict__ wt) {
    int i = blockIdx.x * blockDim.x + threadIdx.x;
    if (i < O_ * H_) {
        int o = i / H_, k = i - o * H_;
        wt[k * O_ + o] = w[i];
    }
}

// ---------------------------------------------------------------- sync prims

// Lane-parallel flag spin: lanes 0..n-1 poll distinct flags, rest replicate
// flag 0; wave proceeds when ALL observed flags >= v. Relaxed agent loads.
__device__ __forceinline__ void flags_wait(const unsigned* f, int n, unsigned v) {
    if (n == 0) return;
    int lane = threadIdx.x & 63;
    const unsigned* p = f + ((lane < n) ? lane : 0);
    for (;;) {
        unsigned x = __hip_atomic_load(p, __ATOMIC_RELAXED, __HIP_MEMORY_SCOPE_AGENT);
        if (__all((int)(x >= v))) break;
        __builtin_amdgcn_s_sleep(2);
    }
    asm volatile("" ::: "memory");
}

// Post completion: drain this block's stores to LLC, then one flag store.
// (The __syncthreads also separates this round's epilogue LDS reads from
// next round's reduce writes.)
__device__ __forceinline__ void post_flag(unsigned* f, unsigned v) {
    asm volatile("s_waitcnt vmcnt(0)" ::: "memory");
    __syncthreads();
    if (threadIdx.x == 0)
        __hip_atomic_store(f, v, __ATOMIC_RELAXED, __HIP_MEMORY_SCOPE_AGENT);
}

// ---------------------------------------------------------------- step
// One layer step for one 32x32 tile. W register-resident (wh/wl), K-split 8.
// CPW chunks of 32 k per wave; chunks [0,SEG0CH) = seg0 (A0), rest = state.
// Loads pipelined PF=4 chunks deep; frags land directly in MFMA input regs.
union Frag { u64 d[2]; bf16x8 v; };

template <int CPW, int SEG0CH, bool CACHED0>
__device__ __forceinline__ void step_full(
    const __bf16* __restrict__ A0h, const __bf16* __restrict__ A0l,  // seg0 planes
    const __bf16* __restrict__ Sh,  const __bf16* __restrict__ Sl,   // state planes
    const bf16x8 (&wh)[CPW][2], const bf16x8 (&wl)[CPW][2],
    const float* __restrict__ bs,
    __bf16* __restrict__ Soh, __bf16* __restrict__ Sol,
    int bt, int jt, int w, float* red,
    const unsigned* ldF, int ldN, unsigned ldV,          // per-wave load deps
    const unsigned* gAF, unsigned gAV,                   // overwrite guard A
    const unsigned* gBF, unsigned gBV)                   // overwrite guard B (opt)
{
    const int lane = threadIdx.x & 63;
    const int ln = lane & 15;
    const int q  = lane >> 4;

    // wait only for the producers of THIS wave's K-chunks
    flags_wait(ldF, ldN, ldV);

    f32x4 acc[2][2][2];
    #pragma unroll
    for (int s = 0; s < 2; ++s)
        #pragma unroll
        for (int n = 0; n < 2; ++n)
            #pragma unroll
            for (int r = 0; r < 2; ++r)
                acc[s][n][r] = (f32x4){0.f, 0.f, 0.f, 0.f};

    constexpr int PF = 4;                  // pipeline depth (chunks)
    Frag SH[PF][2], SL[PF][2];             // [pipe][s]

    auto issue = [&](int c, Frag (&FH)[2], Frag (&FL)[2]) {
        const int gC = w * CPW + c;
        if (gC < SEG0CH) {
            #pragma unroll
            for (int s = 0; s < 2; ++s) {
                long off = ((long)(bt * 2 + s) * (SEG0CH * 4) + gC * 4 + q) * 128 + ln * 8;
                if constexpr (CACHED0) {
                    FH[s].v = *(const bf16x8*)(A0h + off);
                    FL[s].v = *(const bf16x8*)(A0l + off);
                } else {
                    const u64* ph = (const u64*)(A0h + off);
                    const u64* pl = (const u64*)(A0l + off);
                    FH[s].d[0] = __hip_atomic_load(ph,     __ATOMIC_RELAXED, __HIP_MEMORY_SCOPE_AGENT);
                    FH[s].d[1] = __hip_atomic_load(ph + 1, __ATOMIC_RELAXED, __HIP_MEMORY_SCOPE_AGENT);
                    FL[s].d[0] = __hip_atomic_load(pl,     __ATOMIC_RELAXED, __HIP_MEMORY_SCOPE_AGENT);
                    FL[s].d[1] = __hip_atomic_load(pl + 1, __ATOMIC_RELAXED, __HIP_MEMORY_SCOPE_AGENT);
                }
            }
        } else {
            #pragma unroll
            for (int s = 0; s < 2; ++s) {
                long off = ((long)(bt * 2 + s) * 128 + (gC - SEG0CH) * 4 + q) * 128 + ln * 8;
                const u64* ph = (const u64*)(Sh + off);
                const u64* pl = (const u64*)(Sl + off);
                FH[s].d[0] = __hip_atomic_load(ph,     __ATOMIC_RELAXED, __HIP_MEMORY_SCOPE_AGENT);
                FH[s].d[1] = __hip_atomic_load(ph + 1, __ATOMIC_RELAXED, __HIP_MEMORY_SCOPE_AGENT);
                FL[s].d[0] = __hip_atomic_load(pl,     __ATOMIC_RELAXED, __HIP_MEMORY_SCOPE_AGENT);
                FL[s].d[1] = __hip_atomic_load(pl + 1, __ATOMIC_RELAXED, __HIP_MEMORY_SCOPE_AGENT);
            }
        }
    };

    // prologue: fill the pipeline
    #pragma unroll
    for (int i = 0; i < PF; ++i)
        if (i < CPW) issue(i, SH[i], SL[i]);

    #pragma unroll
    for (int c = 0; c < CPW; ++c) {
        bf16x8 ah[2], al[2];
        #pragma unroll
        for (int s = 0; s < 2; ++s) { ah[s] = SH[c & (PF - 1)][s].v; al[s] = SL[c & (PF - 1)][s].v; }
        if (c + PF < CPW) issue(c + PF, SH[c & (PF - 1)], SL[c & (PF - 1)]);
        #pragma unroll
        for (int s = 0; s < 2; ++s)
            #pragma unroll
            for (int n = 0; n < 2; ++n) {
                acc[s][n][0] = __builtin_amdgcn_mfma_f32_16x16x32_bf16(ah[s], wh[c][n], acc[s][n][0], 0, 0, 0);
                acc[s][n][1] = __builtin_amdgcn_mfma_f32_16x16x32_bf16(al[s], wh[c][n], acc[s][n][1], 0, 0, 0);
                acc[s][n][1] = __builtin_amdgcn_mfma_f32_16x16x32_bf16(ah[s], wl[c][n], acc[s][n][1], 0, 0, 0);
            }
    }

    // LDS reduce over 8 K-split waves (pad 34: 8B-aligned float2 reads)
    {
        float* my = red + w * 1088;
        #pragma unroll
        for (int s = 0; s < 2; ++s)
            #pragma unroll
            for (int n = 0; n < 2; ++n) {
                f32x4 sum = acc[s][n][0] + acc[s][n][1];
                #pragma unroll
                for (int r = 0; r < 4; ++r)       // C/D: col=ln, row=q*4+r
                    my[(s * 16 + q * 4 + r) * 34 + n * 16 + ln] = sum[r];
            }
    }
    __syncthreads();

    // overwrite guards: all readers of the buffer we're about to overwrite
    // must have completed (1 round of slack -> almost always satisfied)
    flags_wait(gAF, 32, gAV);
    if (gBF) flags_wait(gBF, 32, gBV);

    // epilogue: 1024 outputs; row = tid>>4, col pair = (tid&15)*2 so that
    // threads jp=0..3 of a row write 16 contiguous bytes (dense full lines)
    {
        int tid = threadIdx.x;
        int row = tid >> 4;                 // 0..31
        int jp  = tid & 15;                 // 0..15
        int c0 = jp * 2;
        float v0 = 0.f, v1 = 0.f;
        #pragma unroll
        for (int w8 = 0; w8 < 8; ++w8) {
            float2 v = *(const float2*)&red[w8 * 1088 + row * 34 + c0];
            v0 += v.x;
            v1 += v.y;
        }
        int j0 = jt * 32 + c0;
        float h0 = tanhf(v0 + bs[j0]);
        float h1v = tanhf(v1 + bs[j0 + 1]);
        union { __bf16 b; unsigned short u; } x0h, x0l, x1h, x1l;
        x0h.b = (__bf16)h0;  x0l.b = (__bf16)(h0 - (float)x0h.b);
        x1h.b = (__bf16)h1v; x1l.b = (__bf16)(h1v - (float)x1h.b);
        unsigned uh = (unsigned)x0h.u | ((unsigned)x1h.u << 16);
        unsigned ul = (unsigned)x0l.u | ((unsigned)x1l.u << 16);
        long idx = ((long)(bt * 2 + (row >> 4)) * 128 + jt * 4 + (c0 >> 3)) * 128
                 + (row & 15) * 8 + (c0 & 7);
        __hip_atomic_store((unsigned*)(Soh + idx), uh, __ATOMIC_RELAXED, __HIP_MEMORY_SCOPE_AGENT);
        __hip_atomic_store((unsigned*)(Sol + idx), ul, __ATOMIC_RELAXED, __HIP_MEMORY_SCOPE_AGENT);
    }
}

// ---------------------------------------------------------------- persistent
struct PArgs {
    const __bf16 *xh, *xl;                // packed X planes, per-t stride 32768
    const __bf16 *Wi0h, *Wi0l, *Wr0h, *Wr0l;
    const __bf16 *Wi1h, *Wi1l, *Wr1h, *Wr1l;
    const float *bs0, *bs1;
    __bf16 *s0ah, *s0al, *s0bh, *s0bl;    // layer0 state planes (double buffer) = h1 alias
    __bf16 *s1ah, *s1al, *s1bh, *s1bl;    // layer1 state planes
    unsigned* bar;
};

// 256 blocks x 512 threads (8 waves), 1 block/CU. 128 layer0 + 128 layer1
// blocks; per layer tiles: 4 bt (m=32) x 32 jt (n=32), K-split 8 over waves.
// Weights live in registers for the whole run (preloaded once).
__global__ __launch_bounds__(512, 2) void persistent_rnn(PArgs a) {
    __shared__ float red[8 * 1088];
    const int w = threadIdx.x >> 6;
    const int lane = threadIdx.x & 63;
    const int ln = lane & 15;
    const int q  = lane >> 4;
    const int layer = blockIdx.x >> 7;
    const int r7 = blockIdx.x & 127;
    const int jt = r7 & 31;
    const int bt = r7 >> 5;
    unsigned* fL0 = a.bar + bt * 64;          // 32 flags per (L0,bt)
    unsigned* fL1 = a.bar + 512 + bt * 64;    // 32 flags per (L1,bt)

    if (layer == 0) {
        // ---- preload W slice: chunks w*5 .. w*5+4 of Ktot=1280 (8 x-chunks, 32 rec)
        bf16x8 wh[5][2], wl[5][2];
        #pragma unroll
        for (int c = 0; c < 5; ++c) {
            int gC = w * 5 + c;
            #pragma unroll
            for (int n = 0; n < 2; ++n) {
                int jr = jt * 32 + n * 16 + ln;
                if (gC < 8) {
                    wh[c][n] = *(const bf16x8*)(a.Wi0h + (long)jr * 256 + gC * 32 + q * 8);
                    wl[c][n] = *(const bf16x8*)(a.Wi0l + (long)jr * 256 + gC * 32 + q * 8);
                } else {
                    wh[c][n] = *(const bf16x8*)(a.Wr0h + (long)jr * 1024 + (gC - 8) * 32 + q * 8);
                    wl[c][n] = *(const bf16x8*)(a.Wr0l + (long)jr * 1024 + (gC - 8) * 32 + q * 8);
                }
            }
        }
        // this wave's state-chunk producers: gC in [max(8,5w), 5w+4] -> jt' = gC-8
        const int pLo = (w * 5 >= 8) ? (w * 5 - 8) : 0;
        const int ldN = (w == 0) ? 0 : (w * 5 - 4 - pLo + 1);
        for (int t = 0; t < T_; ++t) {
            const __bf16* sinh_ = (t & 1) ? a.s0bh : a.s0ah;
            const __bf16* sinl_ = (t & 1) ? a.s0bl : a.s0al;
            __bf16* south      = (t & 1) ? a.s0ah : a.s0bh;
            __bf16* soutl      = (t & 1) ? a.s0al : a.s0bl;
            step_full<5, 8, true>(a.xh + (long)t * 32768, a.xl + (long)t * 32768,
                                  sinh_, sinl_, wh, wl, a.bs0,
                                  south, soutl, bt, jt, w, red,
                                  fL0 + pLo, ldN, (unsigned)t,
                                  fL0, (unsigned)t,
                                  fL1, (t >= 1) ? (unsigned)(t - 1) : 0u);
            post_flag(&fL0[jt], (unsigned)(t + 1));
        }
    } else {
        // ---- preload W slice: chunks w*8 .. w*8+7 of Ktot=2048 (32 h1, 32 rec)
        bf16x8 wh[8][2], wl[8][2];
        #pragma unroll
        for (int c = 0; c < 8; ++c) {
            int gC = w * 8 + c;
            #pragma unroll
            for (int n = 0; n < 2; ++n) {
                int jr = jt * 32 + n * 16 + ln;
                if (gC < 32) {
                    wh[c][n] = *(const bf16x8*)(a.Wi1h + (long)jr * 1024 + gC * 32 + q * 8);
                    wl[c][n] = *(const bf16x8*)(a.Wi1l + (long)jr * 1024 + gC * 32 + q * 8);
                } else {
                    wh[c][n] = *(const bf16x8*)(a.Wr1h + (long)jr * 1024 + (gC - 32) * 32 + q * 8);
                    wl[c][n] = *(const bf16x8*)(a.Wr1l + (long)jr * 1024 + (gC - 32) * 32 + q * 8);
                }
            }
        }
        // waves 0-3: h1 producers fL0[w*8..+7] (need >= r)
        // waves 4-7: state producers fL1[(w-4)*8..+7] (need >= r-1)
        const unsigned* ldF = (w < 4) ? (fL0 + w * 8) : (fL1 + (w - 4) * 8);
        for (int r = 1; r <= T_; ++r) {
            int t1 = r - 1;
            // h1[t1] aliases layer0's sout of round t1 (parity buffer)
            const __bf16* h1h = (t1 & 1) ? a.s0ah : a.s0bh;
            const __bf16* h1l = (t1 & 1) ? a.s0al : a.s0bl;
            const __bf16* sinh_ = (t1 & 1) ? a.s1bh : a.s1ah;
            const __bf16* sinl_ = (t1 & 1) ? a.s1bl : a.s1al;
            __bf16* south       = (t1 & 1) ? a.s1ah : a.s1bh;
            __bf16* soutl       = (t1 & 1) ? a.s1al : a.s1bl;
            unsigned ldV = (w < 4) ? (unsigned)r : (unsigned)(r - 1);
            step_full<8, 32, false>(h1h, h1l, sinh_, sinl_, wh, wl, a.bs1,
                                    south, soutl, bt, jt, w, red,
                                    ldF, 8, ldV,
                                    fL1, (unsigned)(r - 1),
                                    (const unsigned*)nullptr, 0u);
            post_flag(&fL1[jt], (unsigned)r);
        }
    }
}

// ---------------------------------------------------------------- final FC
__global__ __launch_bounds__(128) void fc_kernel(const __bf16* __restrict__ sph,
                                                 const __bf16* __restrict__ spl,
                                                 const float* __restrict__ wt,
                                                 const float* __restrict__ bfc,
                                                 float* __restrict__ out) {
    int b = blockIdx.x;
    int o = threadIdx.x;
    float acc = 0.f;
    #pragma unroll 2
    for (int kg = 0; kg < 128; ++kg) {
        long off = ((long)(b >> 4) * 128 + kg) * 128 + (b & 15) * 8;
        bf16x8 hv = *(const bf16x8*)(sph + off);
        bf16x8 lv = *(const bf16x8*)(spl + off);
        #pragma unroll
        for (int j = 0; j < 8; ++j) {
            float x = (float)hv[j] + (float)lv[j];
            acc += x * wt[(kg * 8 + j) * O_ + o];
        }
    }
    out[b * O_ + o] = acc + bfc[o];
}

// ---------------------------------------------------------------- launch

extern "C" void kernel_launch(void* const* d_in, const int* in_sizes, int n_in,
                              void* d_out, int out_size, void* d_ws, size_t ws_size,
                              hipStream_t stream) {
    const float* X     = (const float*)d_in[0];
    const float* Wih0  = (const float*)d_in[1];
    const float* Whh0  = (const float*)d_in[2];
    const float* bih0  = (const float*)d_in[3];
    const float* bhh0  = (const float*)d_in[4];
    const float* Wih1  = (const float*)d_in[5];
    const float* Whh1  = (const float*)d_in[6];
    const float* bih1  = (const float*)d_in[7];
    const float* bhh1  = (const float*)d_in[8];
    const float* Wfc   = (const float*)d_in[9];
    const float* bfc   = (const float*)d_in[10];
    float* out = (float*)d_out;

    char* p = (char*)d_ws;
    auto alloc = [&](size_t bytes) -> void* {
        void* r = (void*)p;
        p += (bytes + 255) & ~(size_t)255;
        return r;
    };
    const size_t nW0 = (size_t)H_ * I_;
    const size_t nW  = (size_t)H_ * H_;
    const size_t planeSt = (size_t)131072;                  // state plane bf16 count
    __bf16* xh   = (__bf16*)alloc((size_t)T_ * 32768 * 2);  // 16.8 MB
    __bf16* xl   = (__bf16*)alloc((size_t)T_ * 32768 * 2);
    __bf16* W0h  = (__bf16*)alloc(nW0 * 2);
    __bf16* W0l  = (__bf16*)alloc(nW0 * 2);
    __bf16* Wh0h = (__bf16*)alloc(nW * 2);
    __bf16* Wh0l = (__bf16*)alloc(nW * 2);
    __bf16* Wi1h = (__bf16*)alloc(nW * 2);
    __bf16* Wi1l = (__bf16*)alloc(nW * 2);
    __bf16* Wh1h = (__bf16*)alloc(nW * 2);
    __bf16* Wh1l = (__bf16*)alloc(nW * 2);
    __bf16* s0ah = (__bf16*)alloc(planeSt * 2);
    __bf16* s0al = (__bf16*)alloc(planeSt * 2);
    __bf16* s0bh = (__bf16*)alloc(planeSt * 2);
    __bf16* s0bl = (__bf16*)alloc(planeSt * 2);
    __bf16* s1ah = (__bf16*)alloc(planeSt * 2);
    __bf16* s1al = (__bf16*)alloc(planeSt * 2);
    __bf16* s1bh = (__bf16*)alloc(planeSt * 2);
    __bf16* s1bl = (__bf16*)alloc(planeSt * 2);
    float* wfct = (float*)alloc((size_t)H_ * O_ * 4);
    float* bs0  = (float*)alloc((size_t)H_ * 4);
    float* bs1  = (float*)alloc((size_t)H_ * 4);
    unsigned* bar = (unsigned*)alloc(4096);
    (void)ws_size; (void)n_in; (void)in_sizes; (void)out_size;

    pack_x<<<4096, 256, 0, stream>>>(X, xh, xl);
    split_kernel<<<512, 256, 0, stream>>>(Wih0, W0h, W0l, (int)nW0);
    split_kernel<<<1024, 256, 0, stream>>>(Whh0, Wh0h, Wh0l, (int)nW);
    split_kernel<<<1024, 256, 0, stream>>>(Wih1, Wi1h, Wi1l, (int)nW);
    split_kernel<<<1024, 256, 0, stream>>>(Whh1, Wh1h, Wh1l, (int)nW);
    bias_sum_kernel<<<4, 256, 0, stream>>>(bih0, bhh0, bs0, H_);
    bias_sum_kernel<<<4, 256, 0, stream>>>(bih1, bhh1, bs1, H_);
    transpose_fc<<<(O_ * H_ + 255) / 256, 256, 0, stream>>>(Wfc, wfct);

    hipMemsetAsync(s0ah, 0, planeSt * 2, stream);
    hipMemsetAsync(s0al, 0, planeSt * 2, stream);
    hipMemsetAsync(s1ah, 0, planeSt * 2, stream);
    hipMemsetAsync(s1al, 0, planeSt * 2, stream);
    hipMemsetAsync(bar, 0, 4096, stream);

    PArgs args;
    args.xh = xh; args.xl = xl;
    args.Wi0h = W0h; args.Wi0l = W0l; args.Wr0h = Wh0h; args.Wr0l = Wh0l;
    args.Wi1h = Wi1h; args.Wi1l = Wi1l; args.Wr1h = Wh1h; args.Wr1l = Wh1l;
    args.bs0 = bs0; args.bs1 = bs1;
    args.s0ah = s0ah; args.s0al = s0al; args.s0bh = s0bh; args.s0bl = s0bl;
    args.s1ah = s1ah; args.s1al = s1al; args.s1bh = s1bh; args.s1bl = s1bl;
    args.bar = bar;
    void* kp[] = { &args };
    hipLaunchCooperativeKernel((void*)persistent_rnn, dim3(256), dim3(512), kp, 0, stream);

    // final layer1 state: last round r=T_ (t1=255 odd) wrote s1a planes
    fc_kernel<<<B_, O_, 0, stream>>>(s1ah, s1al, wfct, bfc, out);
}

// Round 8
// 2363.836 us; speedup vs baseline: 1.1752x; 1.1752x over previous
//
#include <hip/hip_runtime.h>
#include <stdint.h>
#include <stddef.h>

#define B_ 128
#define T_ 256
#define I_ 256
#define H_ 1024
#define O_ 128

typedef __attribute__((ext_vector_type(8))) __bf16 bf16x8;
typedef __attribute__((ext_vector_type(4))) float f32x4;
typedef unsigned long long u64;

// Split-plane swizzled layout (per plane of K columns, 128 rows, bf16):
//   element (b,k) at bf16 index ((b>>4)*(K/8) + (k>>3))*128 + (b&15)*8 + (k&7)
// => an MFMA A-fragment (lane ln row, k = q*8..q*8+7) is 16 contiguous bytes.
//
// Round 8 memory protocol: producers store state via sc1 atomics (reach LLC)
// then drain + post flag (unchanged, proven). Consumers: after observing
// their dependency flags, ONE acquire-agent fence per block per round
// (buffer_inv: drops stale L1/L2 lines), then PLAIN CACHED loads for
// state/h1. Repeat reads of the same slab by the 32 jt-blocks now hit
// L2 (~200cy) instead of all going LLC-direct (~600-900cy, ~49MB/step).
//
// Sync (R4-R6 proven): per-(layer,bt) 32-arrival counting barrier.
//   L0 round t: wait rel_L0 >= t; fence; compute;
//               pre-epilogue guard rel_L1 >= t-1 (h1-alias readers);
//               arrive L0 (seq t).
//   L1 round r: wait rel_L0 >= r AND rel_L1 >= r-1; fence; compute;
//               arrive L1 (seq r-1).
// All waits target strictly earlier (layer,round) completions -> acyclic.

// ---------------------------------------------------------------- setup

__global__ void split_kernel(const float* __restrict__ src, __bf16* __restrict__ hi,
                             __bf16* __restrict__ lo, int n) {
    int i = blockIdx.x * blockDim.x + threadIdx.x;
    int stride = gridDim.x * blockDim.x;
    for (; i < n; i += stride) {
        float v = src[i];
        __bf16 h = (__bf16)v;
        hi[i] = h;
        lo[i] = (__bf16)(v - (float)h);
    }
}

// X (B,T,I) fp32 -> per-t split planes in fragment layout (K=256)
__global__ void pack_x(const float* __restrict__ X, __bf16* __restrict__ xh,
                       __bf16* __restrict__ xl) {
    int i = blockIdx.x * 256 + threadIdx.x;   // 0 .. 1048575
    int lnidx = i & 15;
    int kg   = (i >> 4) & 31;
    int bgrp = (i >> 9) & 7;
    int t    = i >> 12;
    int b = bgrp * 16 + lnidx;
    const float* xs = X + (long)b * T_ * I_ + (long)t * I_ + kg * 8;
    float4 f0 = *(const float4*)xs;
    float4 f1 = *(const float4*)(xs + 4);
    float f[8] = {f0.x, f0.y, f0.z, f0.w, f1.x, f1.y, f1.z, f1.w};
    bf16x8 hv, lv;
    #pragma unroll
    for (int j = 0; j < 8; ++j) {
        __bf16 h = (__bf16)f[j];
        hv[j] = h;
        lv[j] = (__bf16)(f[j] - (float)h);
    }
    long o = (long)t * 32768 + (long)(bgrp * 32 + kg) * 128 + lnidx * 8;
    *(bf16x8*)(xh + o) = hv;
    *(bf16x8*)(xl + o) = lv;
}

__global__ void bias_sum_kernel(const float* __restrict__ a, const float* __restrict__ b,
                                float* __restrict__ o, int n) {
    int i = blockIdx.x * blockDim.x + threadIdx.x;
    if (i < n) o[i] = a[i] + b[i];
}

__global__ void transpose_fc(const float* __restrict__ w, float* __restrict__ wt) {
    int i = blockIdx.x * blockDim.x + threadIdx.x;
    if (i < O_ * H_) {
        int o = i / H_, k = i - o * H_;
        wt[k * O_ + o] = w[i];
    }
}

// ---------------------------------------------------------------- barrier prims
// slot = layer*4 + bt. cnt = bar[slot*64], rel = bar[slot*64+32].
// Releaser (32nd arriver of seq k) sets rel = k+1. Fence-free relaxed agent
// atomics on the flag words; vmcnt drain before arrive makes data stores
// LLC-visible before the flag can flip.

// Block-wide: spin on up to two release flags, then ONE acquire-agent fence
// (buffer_inv -> L1/L2 stale lines dropped), then barrier.
__device__ __forceinline__ void deps_fence_wait(unsigned* bar, int sA, unsigned vA,
                                                int sB, unsigned vB) {
    if (threadIdx.x == 0) {
        while (__hip_atomic_load(&bar[sA * 64 + 32], __ATOMIC_RELAXED,
                                 __HIP_MEMORY_SCOPE_AGENT) < vA)
            __builtin_amdgcn_s_sleep(2);
        if (sB >= 0) {
            while (__hip_atomic_load(&bar[sB * 64 + 32], __ATOMIC_RELAXED,
                                     __HIP_MEMORY_SCOPE_AGENT) < vB)
                __builtin_amdgcn_s_sleep(2);
        }
        __builtin_amdgcn_fence(__ATOMIC_ACQUIRE, "agent");
    }
    __syncthreads();
    asm volatile("" ::: "memory");
}

__device__ __forceinline__ void bar_arrive(unsigned* bar, int slot, unsigned k) {
    asm volatile("s_waitcnt vmcnt(0)" ::: "memory");
    __syncthreads();
    if (threadIdx.x == 0) {
        unsigned old = __hip_atomic_fetch_add(&bar[slot * 64], 1u, __ATOMIC_RELAXED,
                                              __HIP_MEMORY_SCOPE_AGENT);
        if (old == k * 32u + 31u)
            __hip_atomic_store(&bar[slot * 64 + 32], k + 1u, __ATOMIC_RELAXED,
                               __HIP_MEMORY_SCOPE_AGENT);
    }
}

// ---------------------------------------------------------------- step
// One layer step for one 32x32 tile. W register-resident (wh/wl), K-split 8.
// CPW chunks of 32 k per wave; chunks [0,SEG0CH) = seg0 (A0), rest = state.
// ALL loads plain cached (L1/L2), 16B dwordx4 per plane; PF=4 pipeline.
union Frag { u64 d[2]; bf16x8 v; };

template <int CPW, int SEG0CH>
__device__ __forceinline__ void step_full(
    const __bf16* __restrict__ A0h, const __bf16* __restrict__ A0l,  // seg0 planes
    const __bf16* __restrict__ Sh,  const __bf16* __restrict__ Sl,   // state planes
    const bf16x8 (&wh)[CPW][2], const bf16x8 (&wl)[CPW][2],
    const float* __restrict__ bs,
    __bf16* __restrict__ Soh, __bf16* __restrict__ Sol,
    int bt, int jt, int w, float* red,
    unsigned* bar, int gSlot, unsigned gVal)             // pre-epilogue guard
{
    const int lane = threadIdx.x & 63;
    const int ln = lane & 15;
    const int q  = lane >> 4;

    f32x4 acc[2][2][2];
    #pragma unroll
    for (int s = 0; s < 2; ++s)
        #pragma unroll
        for (int n = 0; n < 2; ++n)
            #pragma unroll
            for (int r = 0; r < 2; ++r)
                acc[s][n][r] = (f32x4){0.f, 0.f, 0.f, 0.f};

    constexpr int PF = 4;                  // pipeline depth (chunks)
    Frag SH[PF][2], SL[PF][2];             // [pipe][s]

    auto issue = [&](int c, Frag (&FH)[2], Frag (&FL)[2]) {
        const int gC = w * CPW + c;
        if (gC < SEG0CH) {
            #pragma unroll
            for (int s = 0; s < 2; ++s) {
                long off = ((long)(bt * 2 + s) * (SEG0CH * 4) + gC * 4 + q) * 128 + ln * 8;
                FH[s].v = *(const bf16x8*)(A0h + off);
                FL[s].v = *(const bf16x8*)(A0l + off);
            }
        } else {
            #pragma unroll
            for (int s = 0; s < 2; ++s) {
                long off = ((long)(bt * 2 + s) * 128 + (gC - SEG0CH) * 4 + q) * 128 + ln * 8;
                FH[s].v = *(const bf16x8*)(Sh + off);
                FL[s].v = *(const bf16x8*)(Sl + off);
            }
        }
    };

    // prologue: fill the pipeline
    #pragma unroll
    for (int i = 0; i < PF; ++i)
        if (i < CPW) issue(i, SH[i], SL[i]);

    #pragma unroll
    for (int c = 0; c < CPW; ++c) {
        bf16x8 ah[2], al[2];
        #pragma unroll
        for (int s = 0; s < 2; ++s) { ah[s] = SH[c & (PF - 1)][s].v; al[s] = SL[c & (PF - 1)][s].v; }
        if (c + PF < CPW) issue(c + PF, SH[c & (PF - 1)], SL[c & (PF - 1)]);
        #pragma unroll
        for (int s = 0; s < 2; ++s)
            #pragma unroll
            for (int n = 0; n < 2; ++n) {
                acc[s][n][0] = __builtin_amdgcn_mfma_f32_16x16x32_bf16(ah[s], wh[c][n], acc[s][n][0], 0, 0, 0);
                acc[s][n][1] = __builtin_amdgcn_mfma_f32_16x16x32_bf16(al[s], wh[c][n], acc[s][n][1], 0, 0, 0);
                acc[s][n][1] = __builtin_amdgcn_mfma_f32_16x16x32_bf16(ah[s], wl[c][n], acc[s][n][1], 0, 0, 0);
            }
    }

    // LDS reduce over 8 K-split waves (pad 34: 8B-aligned float2 reads)
    {
        float* my = red + w * 1088;
        #pragma unroll
        for (int s = 0; s < 2; ++s)
            #pragma unroll
            for (int n = 0; n < 2; ++n) {
                f32x4 sum = acc[s][n][0] + acc[s][n][1];
                #pragma unroll
                for (int r = 0; r < 4; ++r)       // C/D: col=ln, row=q*4+r
                    my[(s * 16 + q * 4 + r) * 34 + n * 16 + ln] = sum[r];
            }
    }
    __syncthreads();

    // pre-epilogue overwrite guard (readers of the buffer we overwrite)
    if (gSlot >= 0) {
        if (threadIdx.x == 0) {
            while (__hip_atomic_load(&bar[gSlot * 64 + 32], __ATOMIC_RELAXED,
                                     __HIP_MEMORY_SCOPE_AGENT) < gVal)
                __builtin_amdgcn_s_sleep(2);
        }
        __syncthreads();
    }

    // epilogue: 1024 outputs; row = tid>>4, col pair = (tid&15)*2 -> threads
    // jp=0..3 of a row write 16 contiguous bytes (dense full lines)
    {
        int tid = threadIdx.x;
        int row = tid >> 4;                 // 0..31
        int jp  = tid & 15;                 // 0..15
        int c0 = jp * 2;
        float v0 = 0.f, v1 = 0.f;
        #pragma unroll
        for (int w8 = 0; w8 < 8; ++w8) {
            float2 v = *(const float2*)&red[w8 * 1088 + row * 34 + c0];
            v0 += v.x;
            v1 += v.y;
        }
        int j0 = jt * 32 + c0;
        float h0 = tanhf(v0 + bs[j0]);
        float h1v = tanhf(v1 + bs[j0 + 1]);
        union { __bf16 b; unsigned short u; } x0h, x0l, x1h, x1l;
        x0h.b = (__bf16)h0;  x0l.b = (__bf16)(h0 - (float)x0h.b);
        x1h.b = (__bf16)h1v; x1l.b = (__bf16)(h1v - (float)x1h.b);
        unsigned uh = (unsigned)x0h.u | ((unsigned)x1h.u << 16);
        unsigned ul = (unsigned)x0l.u | ((unsigned)x1l.u << 16);
        long idx = ((long)(bt * 2 + (row >> 4)) * 128 + jt * 4 + (c0 >> 3)) * 128
                 + (row & 15) * 8 + (c0 & 7);
        __hip_atomic_store((unsigned*)(Soh + idx), uh, __ATOMIC_RELAXED, __HIP_MEMORY_SCOPE_AGENT);
        __hip_atomic_store((unsigned*)(Sol + idx), ul, __ATOMIC_RELAXED, __HIP_MEMORY_SCOPE_AGENT);
    }
}

// ---------------------------------------------------------------- persistent
struct PArgs {
    const __bf16 *xh, *xl;                // packed X planes, per-t stride 32768
    const __bf16 *Wi0h, *Wi0l, *Wr0h, *Wr0l;
    const __bf16 *Wi1h, *Wi1l, *Wr1h, *Wr1l;
    const float *bs0, *bs1;
    __bf16 *s0ah, *s0al, *s0bh, *s0bl;    // layer0 state planes (double buffer) = h1 alias
    __bf16 *s1ah, *s1al, *s1bh, *s1bl;    // layer1 state planes
    unsigned* bar;
};

// 256 blocks x 512 threads (8 waves), 1 block/CU. 128 layer0 + 128 layer1
// blocks; per layer tiles: 4 bt (m=32) x 32 jt (n=32), K-split 8 over waves.
// Weights live in registers for the whole run (preloaded once).
__global__ __launch_bounds__(512, 2) void persistent_rnn(PArgs a) {
    __shared__ float red[8 * 1088];
    const int w = threadIdx.x >> 6;
    const int lane = threadIdx.x & 63;
    const int ln = lane & 15;
    const int q  = lane >> 4;
    const int layer = blockIdx.x >> 7;
    const int r7 = blockIdx.x & 127;
    const int jt = r7 & 31;
    const int bt = r7 >> 5;
    const int slotL0 = 0 * 4 + bt;
    const int slotL1 = 1 * 4 + bt;

    if (layer == 0) {
        // ---- preload W slice: chunks w*5 .. w*5+4 of Ktot=1280 (8 x-chunks, 32 rec)
        bf16x8 wh[5][2], wl[5][2];
        #pragma unroll
        for (int c = 0; c < 5; ++c) {
            int gC = w * 5 + c;
            #pragma unroll
            for (int n = 0; n < 2; ++n) {
                int jr = jt * 32 + n * 16 + ln;
                if (gC < 8) {
                    wh[c][n] = *(const bf16x8*)(a.Wi0h + (long)jr * 256 + gC * 32 + q * 8);
                    wl[c][n] = *(const bf16x8*)(a.Wi0l + (long)jr * 256 + gC * 32 + q * 8);
                } else {
                    wh[c][n] = *(const bf16x8*)(a.Wr0h + (long)jr * 1024 + (gC - 8) * 32 + q * 8);
                    wl[c][n] = *(const bf16x8*)(a.Wr0l + (long)jr * 1024 + (gC - 8) * 32 + q * 8);
                }
            }
        }
        for (int t = 0; t < T_; ++t) {
            const __bf16* sinh_ = (t & 1) ? a.s0bh : a.s0ah;
            const __bf16* sinl_ = (t & 1) ? a.s0bl : a.s0al;
            __bf16* south      = (t & 1) ? a.s0ah : a.s0bh;
            __bf16* soutl      = (t & 1) ? a.s0al : a.s0bl;
            // own-state dependency + acquire fence (inv stale L1/L2)
            deps_fence_wait(a.bar, slotL0, (unsigned)t, -1, 0u);
            step_full<5, 8>(a.xh + (long)t * 32768, a.xl + (long)t * 32768,
                            sinh_, sinl_, wh, wl, a.bs0,
                            south, soutl, bt, jt, w, red,
                            a.bar, slotL1, (t >= 1) ? (unsigned)(t - 1) : 0u);
            bar_arrive(a.bar, slotL0, (unsigned)t);
        }
    } else {
        // ---- preload W slice: chunks w*8 .. w*8+7 of Ktot=2048 (32 h1, 32 rec)
        bf16x8 wh[8][2], wl[8][2];
        #pragma unroll
        for (int c = 0; c < 8; ++c) {
            int gC = w * 8 + c;
            #pragma unroll
            for (int n = 0; n < 2; ++n) {
                int jr = jt * 32 + n * 16 + ln;
                if (gC < 32) {
                    wh[c][n] = *(const bf16x8*)(a.Wi1h + (long)jr * 1024 + gC * 32 + q * 8);
                    wl[c][n] = *(const bf16x8*)(a.Wi1l + (long)jr * 1024 + gC * 32 + q * 8);
                } else {
                    wh[c][n] = *(const bf16x8*)(a.Wr1h + (long)jr * 1024 + (gC - 32) * 32 + q * 8);
                    wl[c][n] = *(const bf16x8*)(a.Wr1l + (long)jr * 1024 + (gC - 32) * 32 + q * 8);
                }
            }
        }
        for (int r = 1; r <= T_; ++r) {
            int t1 = r - 1;
            // h1[t1] aliases layer0's sout of round t1 (parity buffer)
            const __bf16* h1h = (t1 & 1) ? a.s0ah : a.s0bh;
            const __bf16* h1l = (t1 & 1) ? a.s0al : a.s0bl;
            const __bf16* sinh_ = (t1 & 1) ? a.s1bh : a.s1ah;
            const __bf16* sinl_ = (t1 & 1) ? a.s1bl : a.s1al;
            __bf16* south       = (t1 & 1) ? a.s1ah : a.s1bh;
            __bf16* soutl       = (t1 & 1) ? a.s1al : a.s1bl;
            // h1 producers + own state, then acquire fence
            deps_fence_wait(a.bar, slotL0, (unsigned)r,
                            slotL1, (r >= 2) ? (unsigned)(r - 1) : 0u);
            step_full<8, 32>(h1h, h1l, sinh_, sinl_, wh, wl, a.bs1,
                             south, soutl, bt, jt, w, red,
                             a.bar, -1, 0u);   // guard implied by top wait
            bar_arrive(a.bar, slotL1, (unsigned)(r - 1));
        }
    }
}

// ---------------------------------------------------------------- final FC
__global__ __launch_bounds__(128) void fc_kernel(const __bf16* __restrict__ sph,
                                                 const __bf16* __restrict__ spl,
                                                 const float* __restrict__ wt,
                                                 const float* __restrict__ bfc,
                                                 float* __restrict__ out) {
    int b = blockIdx.x;
    int o = threadIdx.x;
    float acc = 0.f;
    #pragma unroll 2
    for (int kg = 0; kg < 128; ++kg) {
        long off = ((long)(b >> 4) * 128 + kg) * 128 + (b & 15) * 8;
        bf16x8 hv = *(const bf16x8*)(sph + off);
        bf16x8 lv = *(const bf16x8*)(spl + off);
        #pragma unroll
        for (int j = 0; j < 8; ++j) {
            float x = (float)hv[j] + (float)lv[j];
            acc += x * wt[(kg * 8 + j) * O_ + o];
        }
    }
    out[b * O_ + o] = acc + bfc[o];
}

// ---------------------------------------------------------------- launch

extern "C" void kernel_launch(void* const* d_in, const int* in_sizes, int n_in,
                              void* d_out, int out_size, void* d_ws, size_t ws_size,
                              hipStream_t stream) {
    const float* X     = (const float*)d_in[0];
    const float* Wih0  = (const float*)d_in[1];
    const float* Whh0  = (const float*)d_in[2];
    const float* bih0  = (const float*)d_in[3];
    const float* bhh0  = (const float*)d_in[4];
    const float* Wih1  = (const float*)d_in[5];
    const float* Whh1  = (const float*)d_in[6];
    const float* bih1  = (const float*)d_in[7];
    const float* bhh1  = (const float*)d_in[8];
    const float* Wfc   = (const float*)d_in[9];
    const float* bfc   = (const float*)d_in[10];
    float* out = (float*)d_out;

    char* p = (char*)d_ws;
    auto alloc = [&](size_t bytes) -> void* {
        void* r = (void*)p;
        p += (bytes + 255) & ~(size_t)255;
        return r;
    };
    const size_t nW0 = (size_t)H_ * I_;
    const size_t nW  = (size_t)H_ * H_;
    const size_t planeSt = (size_t)131072;                  // state plane bf16 count
    __bf16* xh   = (__bf16*)alloc((size_t)T_ * 32768 * 2);  // 16.8 MB
    __bf16* xl   = (__bf16*)alloc((size_t)T_ * 32768 * 2);
    __bf16* W0h  = (__bf16*)alloc(nW0 * 2);
    __bf16* W0l  = (__bf16*)alloc(nW0 * 2);
    __bf16* Wh0h = (__bf16*)alloc(nW * 2);
    __bf16* Wh0l = (__bf16*)alloc(nW * 2);
    __bf16* Wi1h = (__bf16*)alloc(nW * 2);
    __bf16* Wi1l = (__bf16*)alloc(nW * 2);
    __bf16* Wh1h = (__bf16*)alloc(nW * 2);
    __bf16* Wh1l = (__bf16*)alloc(nW * 2);
    __bf16* s0ah = (__bf16*)alloc(planeSt * 2);
    __bf16* s0al = (__bf16*)alloc(planeSt * 2);
    __bf16* s0bh = (__bf16*)alloc(planeSt * 2);
    __bf16* s0bl = (__bf16*)alloc(planeSt * 2);
    __bf16* s1ah = (__bf16*)alloc(planeSt * 2);
    __bf16* s1al = (__bf16*)alloc(planeSt * 2);
    __bf16* s1bh = (__bf16*)alloc(planeSt * 2);
    __bf16* s1bl = (__bf16*)alloc(planeSt * 2);
    float* wfct = (float*)alloc((size_t)H_ * O_ * 4);
    float* bs0  = (float*)alloc((size_t)H_ * 4);
    float* bs1  = (float*)alloc((size_t)H_ * 4);
    unsigned* bar = (unsigned*)alloc(4096);
    (void)ws_size; (void)n_in; (void)in_sizes; (void)out_size;

    pack_x<<<4096, 256, 0, stream>>>(X, xh, xl);
    split_kernel<<<512, 256, 0, stream>>>(Wih0, W0h, W0l, (int)nW0);
    split_kernel<<<1024, 256, 0, stream>>>(Whh0, Wh0h, Wh0l, (int)nW);
    split_kernel<<<1024, 256, 0, stream>>>(Wih1, Wi1h, Wi1l, (int)nW);
    split_kernel<<<1024, 256, 0, stream>>>(Whh1, Wh1h, Wh1l, (int)nW);
    bias_sum_kernel<<<4, 256, 0, stream>>>(bih0, bhh0, bs0, H_);
    bias_sum_kernel<<<4, 256, 0, stream>>>(bih1, bhh1, bs1, H_);
    transpose_fc<<<(O_ * H_ + 255) / 256, 256, 0, stream>>>(Wfc, wfct);

    hipMemsetAsync(s0ah, 0, planeSt * 2, stream);
    hipMemsetAsync(s0al, 0, planeSt * 2, stream);
    hipMemsetAsync(s1ah, 0, planeSt * 2, stream);
    hipMemsetAsync(s1al, 0, planeSt * 2, stream);
    hipMemsetAsync(bar, 0, 4096, stream);

    PArgs args;
    args.xh = xh; args.xl = xl;
    args.Wi0h = W0h; args.Wi0l = W0l; args.Wr0h = Wh0h; args.Wr0l = Wh0l;
    args.Wi1h = Wi1h; args.Wi1l = Wi1l; args.Wr1h = Wh1h; args.Wr1l = Wh1l;
    args.bs0 = bs0; args.bs1 = bs1;
    args.s0ah = s0ah; args.s0al = s0al; args.s0bh = s0bh; args.s0bl = s0bl;
    args.s1ah = s1ah; args.s1al = s1al; args.s1bh = s1bh; args.s1bl = s1bl;
    args.bar = bar;
    void* kp[] = { &args };
    hipLaunchCooperativeKernel((void*)persistent_rnn, dim3(256), dim3(512), kp, 0, stream);

    // final layer1 state: last round r=T_ (t1=255 odd) wrote s1a planes
    fc_kernel<<<B_, O_, 0, stream>>>(s1ah, s1al, wfct, bfc, out);
}

// Round 9
// 1960.139 us; speedup vs baseline: 1.4172x; 1.2060x over previous
//
#include <hip/hip_runtime.h>
#include <stdint.h>
#include <stddef.h>

#define B_ 128
#define T_ 256
#define I_ 256
#define H_ 1024
#define O_ 128

typedef __attribute__((ext_vector_type(8))) __bf16 bf16x8;
typedef __attribute__((ext_vector_type(4))) float f32x4;
typedef unsigned long long u64;

// Packed-swizzled layout for state/x (per buffer of K columns, 128 rows):
//   element (b,k): u64 idx = (b>>4)*(K/2)*16 + (k>>1)*16 + (b&15)
//   u64 = dword(k even) | dword(k odd)<<32 ; dword = hi_bits | lo_bits<<16
//
// h1[t] is aliased to layer0's state double-buffer (identical content &
// layout); parity(t) buffer is only overwritten at layer0 round t+2, and
// the per-bt domain barrier (64 arrivals: 32 L0 + 32 L1 blocks) at round
// t+1 orders layer1's round-(t+1) readers first.
//
// This is the session-best round-1 structure (1890us steady) restored,
// with one local change: merged low-order accumulator (al*wh and ah*wl
// share acc[1]; numerically identical, -16 AGPR, one less vector add).

// ---------------------------------------------------------------- setup

__global__ void split_kernel(const float* __restrict__ src, __bf16* __restrict__ hi,
                             __bf16* __restrict__ lo, int n) {
    int i = blockIdx.x * blockDim.x + threadIdx.x;
    int stride = gridDim.x * blockDim.x;
    for (; i < n; i += stride) {
        float v = src[i];
        __bf16 h = (__bf16)v;
        hi[i] = h;
        lo[i] = (__bf16)(v - (float)h);
    }
}

// X (B,T,I) fp32 -> packed-swizzled per t: xp[t][b>>4][k>>1][b&15]
__global__ void pack_x(const float* __restrict__ X, u64* __restrict__ xp) {
    int i = blockIdx.x * 256 + threadIdx.x;           // 0 .. 4194303
    int ln = i & 15;
    int k2 = (i >> 4) & 127;
    int bt16 = (i >> 11) & 7;
    int t = i >> 14;
    int b = bt16 * 16 + ln;
    long xo = (long)b * T_ * I_ + (long)t * I_ + k2 * 2;
    float v0 = X[xo], v1 = X[xo + 1];
    union { __bf16 b; unsigned short u; } h0, l0, h1, l1;
    h0.b = (__bf16)v0; l0.b = (__bf16)(v0 - (float)h0.b);
    h1.b = (__bf16)v1; l1.b = (__bf16)(v1 - (float)h1.b);
    u64 pk = (u64)((unsigned)h0.u | ((unsigned)l0.u << 16))
           | ((u64)((unsigned)h1.u | ((unsigned)l1.u << 16)) << 32);
    xp[(long)t * 16384 + bt16 * 2048 + k2 * 16 + ln] = pk;
}

__global__ void bias_sum_kernel(const float* __restrict__ a, const float* __restrict__ b,
                                float* __restrict__ o, int n) {
    int i = blockIdx.x * blockDim.x + threadIdx.x;
    if (i < n) o[i] = a[i] + b[i];
}

__global__ void transpose_fc(const float* __restrict__ w, float* __restrict__ wt) {
    int i = blockIdx.x * blockDim.x + threadIdx.x;
    if (i < O_ * H_) {
        int o = i / H_, k = i - o * H_;
        wt[k * O_ + o] = w[i];
    }
}

// ---------------------------------------------------------------- loaders

__device__ __forceinline__ void unpack4(const u64* d, bf16x8* hi, bf16x8* lo) {
    union { unsigned u[4]; bf16x8 v; } Hh, Ll;
    #pragma unroll
    for (int i = 0; i < 4; ++i) {
        unsigned lo32 = (unsigned)d[i], hi32 = (unsigned)(d[i] >> 32);
        Hh.u[i] = (lo32 & 0xFFFFu) | (hi32 << 16);
        Ll.u[i] = (lo32 >> 16) | (hi32 & 0xFFFF0000u);
    }
    *hi = Hh.v; *lo = Ll.v;
}

// sc1 LLC-coherent loads (state/h1 written mid-kernel by other blocks)
__device__ __forceinline__ void load_swz(const u64* p, bf16x8* hi, bf16x8* lo) {
    u64 d[4];
    #pragma unroll
    for (int i = 0; i < 4; ++i)
        d[i] = __hip_atomic_load((u64*)p + i * 16, __ATOMIC_RELAXED,
                                 __HIP_MEMORY_SCOPE_AGENT);
    unpack4(d, hi, lo);
}

// plain cached loads (x: written before kernel launch, LLC-visible)
__device__ __forceinline__ void load_swz_cached(const u64* p, bf16x8* hi, bf16x8* lo) {
    u64 d[4];
    #pragma unroll
    for (int i = 0; i < 4; ++i)
        d[i] = p[i * 16];
    unpack4(d, hi, lo);
}

// ---------------------------------------------------------------- step
// One layer step for one 32x32 tile. W register-resident (wh/wl), K-split 8.
// CPW chunks of 32 k per wave; chunks [0,SEG0CH) = seg0 (A0), rest = state.
template <int CPW, int SEG0CH, bool CACHED0>
__device__ __forceinline__ void step_full(
    const u64* __restrict__ A0,            // packed seg0 (xp_t or h1 alias)
    const u64* __restrict__ Sp,            // packed state (K=1024)
    const bf16x8 (&wh)[CPW][2], const bf16x8 (&wl)[CPW][2],
    const float* __restrict__ bs,
    u64* __restrict__ So,
    int bt, int jt, int w, float* red)
{
    const int lane = threadIdx.x & 63;
    const int ln = lane & 15;
    const int q  = lane >> 4;

    f32x4 acc[2][2][2];
    #pragma unroll
    for (int s = 0; s < 2; ++s)
        #pragma unroll
        for (int n = 0; n < 2; ++n)
            #pragma unroll
            for (int r = 0; r < 2; ++r)
                acc[s][n][r] = (f32x4){0.f, 0.f, 0.f, 0.f};

    constexpr int PF = 2;                  // pipeline depth (chunks)
    u64 d[PF][2][4];

    auto issue = [&](int c, u64 (&dst)[2][4]) {
        const int gC = w * CPW + c;
        if (gC < SEG0CH) {
            const u64* base = A0 + (long)(gC * 16 + q * 4) * 16 + ln;
            #pragma unroll
            for (int s = 0; s < 2; ++s) {
                const u64* p = base + (long)(bt * 2 + s) * (SEG0CH * 256);
                #pragma unroll
                for (int i = 0; i < 4; ++i) {
                    if (CACHED0) dst[s][i] = p[i * 16];
                    else dst[s][i] = __hip_atomic_load((u64*)p + i * 16,
                                         __ATOMIC_RELAXED, __HIP_MEMORY_SCOPE_AGENT);
                }
            }
        } else {
            const u64* base = Sp + (long)((gC - SEG0CH) * 16 + q * 4) * 16 + ln;
            #pragma unroll
            for (int s = 0; s < 2; ++s) {
                const u64* p = base + (long)(bt * 2 + s) * 8192;
                #pragma unroll
                for (int i = 0; i < 4; ++i)
                    dst[s][i] = __hip_atomic_load((u64*)p + i * 16,
                                    __ATOMIC_RELAXED, __HIP_MEMORY_SCOPE_AGENT);
            }
        }
    };

    issue(0, d[0]);
    issue(1, d[1]);                        // CPW >= 2 always (5 or 8)

    #pragma unroll
    for (int c = 0; c < CPW; ++c) {
        bf16x8 ah[2], al[2];
        #pragma unroll
        for (int s = 0; s < 2; ++s)
            unpack4(d[c & 1][s], &ah[s], &al[s]);
        if (c + PF < CPW) issue(c + PF, d[c & 1]);
        #pragma unroll
        for (int s = 0; s < 2; ++s)
            #pragma unroll
            for (int n = 0; n < 2; ++n) {
                acc[s][n][0] = __builtin_amdgcn_mfma_f32_16x16x32_bf16(ah[s], wh[c][n], acc[s][n][0], 0, 0, 0);
                acc[s][n][1] = __builtin_amdgcn_mfma_f32_16x16x32_bf16(al[s], wh[c][n], acc[s][n][1], 0, 0, 0);
                acc[s][n][1] = __builtin_amdgcn_mfma_f32_16x16x32_bf16(ah[s], wl[c][n], acc[s][n][1], 0, 0, 0);
            }
    }

    // LDS reduce over 8 K-split waves (pad 33)
    {
        float* my = red + w * 1056;
        #pragma unroll
        for (int s = 0; s < 2; ++s)
            #pragma unroll
            for (int n = 0; n < 2; ++n) {
                f32x4 sum = acc[s][n][0] + acc[s][n][1];
                #pragma unroll
                for (int r = 0; r < 4; ++r)       // C/D: col=ln, row=q*4+r
                    my[(s * 16 + q * 4 + r) * 33 + n * 16 + ln] = sum[r];
            }
    }
    __syncthreads();

    // epilogue: 1024 outputs = 512 u64 (pairs), one per thread
    {
        int tid = threadIdx.x;
        int row = tid & 31;
        int jp  = tid >> 5;                 // 0..15
        int c0 = jp * 2;
        float v0 = 0.f, v1 = 0.f;
        #pragma unroll
        for (int w8 = 0; w8 < 8; ++w8) {
            v0 += red[w8 * 1056 + row * 33 + c0];
            v1 += red[w8 * 1056 + row * 33 + c0 + 1];
        }
        int j0 = jt * 32 + c0;
        float h0 = tanhf(v0 + bs[j0]);
        float h1v = tanhf(v1 + bs[j0 + 1]);
        union { __bf16 b; unsigned short u; } x0h, x0l, x1h, x1l;
        x0h.b = (__bf16)h0;  x0l.b = (__bf16)(h0 - (float)x0h.b);
        x1h.b = (__bf16)h1v; x1l.b = (__bf16)(h1v - (float)x1h.b);
        u64 pk = (u64)((unsigned)x0h.u | ((unsigned)x0l.u << 16))
               | ((u64)((unsigned)x1h.u | ((unsigned)x1l.u << 16)) << 32);
        long idx = (long)(bt * 2 + (row >> 4)) * 8192 + (long)(jt * 16 + jp) * 16 + (row & 15);
        __hip_atomic_store(&So[idx], pk, __ATOMIC_RELAXED, __HIP_MEMORY_SCOPE_AGENT);
    }
}

// ---------------------------------------------------------------- barrier
// Per-bt domain barrier: 64 blocks (32 layer0 + 32 layer1 sharing the same
// 32 batch rows). Single level: one arrive counter + one release flag per
// domain, on separate LLC lines. Fence-free (relaxed agent atomics meet at
// LLC); vmcnt drain before arrive guarantees stores are LLC-visible.
__device__ __forceinline__ void domain_barrier(unsigned* bar, int dom, unsigned step) {
    asm volatile("s_waitcnt vmcnt(0)" ::: "memory");
    __syncthreads();
    if (threadIdx.x == 0) {
        unsigned tgt = step + 1u;
        unsigned old = __hip_atomic_fetch_add(&bar[dom * 64], 1u, __ATOMIC_RELAXED,
                                              __HIP_MEMORY_SCOPE_AGENT);
        if (old == step * 64u + 63u)
            __hip_atomic_store(&bar[dom * 64 + 32], tgt, __ATOMIC_RELAXED,
                               __HIP_MEMORY_SCOPE_AGENT);
        while (__hip_atomic_load(&bar[dom * 64 + 32], __ATOMIC_RELAXED,
                                 __HIP_MEMORY_SCOPE_AGENT) < tgt)
            __builtin_amdgcn_s_sleep(2);
    }
    __syncthreads();
    asm volatile("" ::: "memory");
}

// ---------------------------------------------------------------- persistent
struct PArgs {
    const u64* xp;                        // packed X [t][bt16][k2][ln]
    const __bf16 *Wi0h, *Wi0l, *Wr0h, *Wr0l;
    const __bf16 *Wi1h, *Wi1l, *Wr1h, *Wr1l;
    const float *bs0, *bs1;
    u64 *s0a, *s0b, *s1a, *s1b;           // s0* doubles as h1 (aliased)
    unsigned* bar;
};

// 256 blocks x 512 threads (8 waves), 1 block/CU. 128 layer0 + 128 layer1
// blocks; per layer tiles: 4 bt (m=32) x 32 jt (n=32), K-split 8 over waves.
// Weights live in registers for the whole run (preloaded once).
__global__ __launch_bounds__(512, 2) void persistent_rnn(PArgs a) {
    __shared__ float red[8 * 1056];
    const int w = threadIdx.x >> 6;
    const int lane = threadIdx.x & 63;
    const int ln = lane & 15;
    const int q  = lane >> 4;
    const int layer = blockIdx.x >> 7;
    const int r7 = blockIdx.x & 127;
    const int jt = r7 & 31;
    const int bt = r7 >> 5;

    if (layer == 0) {
        // ---- preload W slice: chunks w*5 .. w*5+4 of Ktot=1280 (8 x-chunks, 32 rec)
        bf16x8 wh[5][2], wl[5][2];
        #pragma unroll
        for (int c = 0; c < 5; ++c) {
            int gC = w * 5 + c;
            #pragma unroll
            for (int n = 0; n < 2; ++n) {
                int jr = jt * 32 + n * 16 + ln;
                if (gC < 8) {
                    wh[c][n] = *(const bf16x8*)(a.Wi0h + (long)jr * 256 + gC * 32 + q * 8);
                    wl[c][n] = *(const bf16x8*)(a.Wi0l + (long)jr * 256 + gC * 32 + q * 8);
                } else {
                    wh[c][n] = *(const bf16x8*)(a.Wr0h + (long)jr * 1024 + (gC - 8) * 32 + q * 8);
                    wl[c][n] = *(const bf16x8*)(a.Wr0l + (long)jr * 1024 + (gC - 8) * 32 + q * 8);
                }
            }
        }
        for (int t = 0; t < T_; ++t) {
            const u64* sin = (t & 1) ? a.s0b : a.s0a;
            u64* sout      = (t & 1) ? a.s0a : a.s0b;
            step_full<5, 8, true>(a.xp + (long)t * 16384, sin, wh, wl, a.bs0,
                                  sout, bt, jt, w, red);
            domain_barrier(a.bar, bt, (unsigned)t);
        }
    } else {
        // ---- preload W slice: chunks w*8 .. w*8+7 of Ktot=2048 (32 h1, 32 rec)
        bf16x8 wh[8][2], wl[8][2];
        #pragma unroll
        for (int c = 0; c < 8; ++c) {
            int gC = w * 8 + c;
            #pragma unroll
            for (int n = 0; n < 2; ++n) {
                int jr = jt * 32 + n * 16 + ln;
                if (gC < 32) {
                    wh[c][n] = *(const bf16x8*)(a.Wi1h + (long)jr * 1024 + gC * 32 + q * 8);
                    wl[c][n] = *(const bf16x8*)(a.Wi1l + (long)jr * 1024 + gC * 32 + q * 8);
                } else {
                    wh[c][n] = *(const bf16x8*)(a.Wr1h + (long)jr * 1024 + (gC - 32) * 32 + q * 8);
                    wl[c][n] = *(const bf16x8*)(a.Wr1l + (long)jr * 1024 + (gC - 32) * 32 + q * 8);
                }
            }
        }
        domain_barrier(a.bar, bt, 0u);
        for (int t = 1; t <= T_; ++t) {
            int t1 = t - 1;
            // h1[t1] aliases layer0's sout of round t1: parity buffer
            const u64* h1in = (t1 & 1) ? a.s0a : a.s0b;
            const u64* sin  = (t1 & 1) ? a.s1b : a.s1a;
            u64* sout       = (t1 & 1) ? a.s1a : a.s1b;
            step_full<8, 32, false>(h1in, sin, wh, wl, a.bs1,
                                    sout, bt, jt, w, red);
            if (t < T_) domain_barrier(a.bar, bt, (unsigned)t);
        }
    }
}

// ---------------------------------------------------------------- final FC
__global__ __launch_bounds__(128) void fc_kernel(const u64* __restrict__ sp,
                                                 const float* __restrict__ wt,
                                                 const float* __restrict__ bfc,
                                                 float* __restrict__ out) {
    int b = blockIdx.x;
    int o = threadIdx.x;
    int bt = b >> 4, r = b & 15;
    float acc = 0.f;
    #pragma unroll 4
    for (int k2 = 0; k2 < H_ / 2; ++k2) {
        u64 pk = __hip_atomic_load((u64*)sp + (long)bt * 8192 + (long)k2 * 16 + r,
                                   __ATOMIC_RELAXED, __HIP_MEMORY_SCOPE_AGENT);
        union { unsigned short u; __bf16 bf; } hh, hl;
        unsigned lo32 = (unsigned)pk, hi32 = (unsigned)(pk >> 32);
        hh.u = (unsigned short)(lo32 & 0xFFFF); hl.u = (unsigned short)(lo32 >> 16);
        float x0 = (float)hh.bf + (float)hl.bf;
        hh.u = (unsigned short)(hi32 & 0xFFFF); hl.u = (unsigned short)(hi32 >> 16);
        float x1 = (float)hh.bf + (float)hl.bf;
        acc += x0 * wt[(2 * k2) * O_ + o] + x1 * wt[(2 * k2 + 1) * O_ + o];
    }
    out[b * O_ + o] = acc + bfc[o];
}

// ---------------------------------------------------------------- launch

extern "C" void kernel_launch(void* const* d_in, const int* in_sizes, int n_in,
                              void* d_out, int out_size, void* d_ws, size_t ws_size,
                              hipStream_t stream) {
    const float* X     = (const float*)d_in[0];
    const float* Wih0  = (const float*)d_in[1];
    const float* Whh0  = (const float*)d_in[2];
    const float* bih0  = (const float*)d_in[3];
    const float* bhh0  = (const float*)d_in[4];
    const float* Wih1  = (const float*)d_in[5];
    const float* Whh1  = (const float*)d_in[6];
    const float* bih1  = (const float*)d_in[7];
    const float* bhh1  = (const float*)d_in[8];
    const float* Wfc   = (const float*)d_in[9];
    const float* bfc   = (const float*)d_in[10];
    float* out = (float*)d_out;

    char* p = (char*)d_ws;
    auto alloc = [&](size_t bytes) -> void* {
        void* r = (void*)p;
        p += (bytes + 255) & ~(size_t)255;
        return r;
    };
    const size_t nW0 = (size_t)H_ * I_;
    const size_t nW  = (size_t)H_ * H_;
    u64* xp      = (u64*)alloc((size_t)T_ * 16384 * 8);     // 33.5 MB
    __bf16* W0h  = (__bf16*)alloc(nW0 * 2);
    __bf16* W0l  = (__bf16*)alloc(nW0 * 2);
    __bf16* Wh0h = (__bf16*)alloc(nW * 2);
    __bf16* Wh0l = (__bf16*)alloc(nW * 2);
    __bf16* Wi1h = (__bf16*)alloc(nW * 2);
    __bf16* Wi1l = (__bf16*)alloc(nW * 2);
    __bf16* Wh1h = (__bf16*)alloc(nW * 2);
    __bf16* Wh1l = (__bf16*)alloc(nW * 2);
    u64* s0a  = (u64*)alloc(65536 * 8);
    u64* s0b  = (u64*)alloc(65536 * 8);
    u64* s1a  = (u64*)alloc(65536 * 8);
    u64* s1b  = (u64*)alloc(65536 * 8);
    float* wfct = (float*)alloc((size_t)H_ * O_ * 4);
    float* bs0  = (float*)alloc((size_t)H_ * 4);
    float* bs1  = (float*)alloc((size_t)H_ * 4);
    unsigned* bar = (unsigned*)alloc(4096);
    (void)ws_size; (void)n_in; (void)in_sizes; (void)out_size;

    pack_x<<<16384, 256, 0, stream>>>(X, xp);
    split_kernel<<<512, 256, 0, stream>>>(Wih0, W0h, W0l, (int)nW0);
    split_kernel<<<1024, 256, 0, stream>>>(Whh0, Wh0h, Wh0l, (int)nW);
    split_kernel<<<1024, 256, 0, stream>>>(Wih1, Wi1h, Wi1l, (int)nW);
    split_kernel<<<1024, 256, 0, stream>>>(Whh1, Wh1h, Wh1l, (int)nW);
    bias_sum_kernel<<<4, 256, 0, stream>>>(bih0, bhh0, bs0, H_);
    bias_sum_kernel<<<4, 256, 0, stream>>>(bih1, bhh1, bs1, H_);
    transpose_fc<<<(O_ * H_ + 255) / 256, 256, 0, stream>>>(Wfc, wfct);

    hipMemsetAsync(s0a, 0, 65536 * 8, stream);
    hipMemsetAsync(s1a, 0, 65536 * 8, stream);
    hipMemsetAsync(bar, 0, 4096, stream);

    PArgs args;
    args.xp = xp;
    args.Wi0h = W0h; args.Wi0l = W0l; args.Wr0h = Wh0h; args.Wr0l = Wh0l;
    args.Wi1h = Wi1h; args.Wi1l = Wi1l; args.Wr1h = Wh1h; args.Wr1l = Wh1l;
    args.bs0 = bs0; args.bs1 = bs1;
    args.s0a = s0a; args.s0b = s0b; args.s1a = s1a; args.s1b = s1b;
    args.bar = bar;
    void* kp[] = { &args };
    hipLaunchCooperativeKernel((void*)persistent_rnn, dim3(256), dim3(512), kp, 0, stream);

    // final layer1 state: last t1=255 (odd) wrote s1a
    fc_kernel<<<B_, O_, 0, stream>>>(s1a, wfct, bfc, out);
}